// Round 19
// baseline (59.240 us; speedup 1.0000x reference)
//
#include <hip/hip_runtime.h>

// CG tensor product, fully fused MFMA design (round 19):
//  = round 18 (52.1 us session best) + B-REGISTER PREFETCH: stage-2 B
//    fragments for triple ti+1 are loaded into VGPRs BEFORE the barrier
//    (they don't depend on stage-1), hiding their L2 latency under the
//    barrier + next stage-1 instead of exposing it after the barrier.
//  k0_pack:  W f32 [l][k][o] -> fragment-major bf16 Wfrag (LDS transpose)
//  kcg:      Racah CG coefficients -> f32 table in ws (fp64 isolated here)
//  fused_all: 1536 blocks = 6 l-groups x 256 z.
// Fallback: round-1 fused VALU kernel if ws too small.

#define NL 6

__constant__ int d_CUM_W_rt[NL]  = {0,49152,131072,237568,352256,466944};
__constant__ int d_OUT_OFF_rt[NL]= {0,32,128,288,512,800};
__constant__ int d_NTRI_rt[NL]   = {6,10,13,14,14,12};
__constant__ int d_TRI_START_rt[NL] = {0,6,16,29,43,57};
__constant__ int d_TRI_L_rt[69] = {
  0,0,0,0,0,0,
  1,1,1,1,1,1,1,1,1,1,
  2,2,2,2,2,2,2,2,2,2,2,2,2,
  3,3,3,3,3,3,3,3,3,3,3,3,3,3,
  4,4,4,4,4,4,4,4,4,4,4,4,4,4,
  5,5,5,5,5,5,5,5,5,5,5,5};
__constant__ int d_TRI_L1_rt[69] = {
  0,1,2,3,4,5,
  0,1,1,2,2,3,3,4,4,5,
  0,1,1,1,2,2,2,3,3,3,4,4,5,
  0,1,1,1,2,2,2,2,3,3,3,4,4,5,
  0,1,1,1,2,2,2,2,3,3,3,4,4,5,
  0,1,1,2,2,2,3,3,3,4,4,5};
__constant__ int d_TRI_L2_rt[69] = {
  0,1,2,3,4,5,
  1,1,2,2,3,3,4,4,5,5,
  2,1,2,3,2,3,4,3,4,5,4,5,5,
  3,2,3,4,2,3,4,5,3,4,5,4,5,5,
  4,3,4,5,2,3,4,5,3,4,5,4,5,5,
  5,4,5,3,4,5,3,4,5,4,5,5};
// cumulative offsets of NM*N1 CG entries per global triple
__constant__ int d_CG_OFF_rt[69] = {
  0,1,4,9,16,25,
  36,39,48,57,72,87,108,129,156,183,
  216,221,236,251,266,291,316,341,376,411,446,491,536,
  591,598,619,640,661,696,731,766,801,850,899,948,1011,1074,
  1151,1160,1187,1214,1241,1286,1331,1376,1421,1484,1547,1610,1691,1772,
  1871,1882,1915,1948,2003,2058,2113,2190,2267,2344,2443,2542};
// total CG entries: 2663

__constant__ double d_FACT[17] = {
  1.0,1.0,2.0,6.0,24.0,120.0,720.0,5040.0,40320.0,362880.0,
  3628800.0,39916800.0,479001600.0,6227020800.0,87178291200.0,
  1307674368000.0,20922789888000.0};

__device__ __forceinline__ int imax(int a, int b){ return a > b ? a : b; }
__device__ __forceinline__ int imin(int a, int b){ return a < b ? a : b; }
__device__ __forceinline__ constexpr int cumf(int l) {
  return l==0?0 : l==1?16 : l==2?64 : l==3?144 : l==4?256 : 400;
}

__device__ float cg_coef(int l1, int m1, int l2, int m2, int l, int m) {
  double pre = sqrt((double)(2*l+1) * d_FACT[l+l1-l2] * d_FACT[l-l1+l2] *
                    d_FACT[l1+l2-l] / d_FACT[l1+l2+l+1]);
  pre *= sqrt(d_FACT[l+m]*d_FACT[l-m]*d_FACT[l1-m1]*d_FACT[l1+m1]*
              d_FACT[l2-m2]*d_FACT[l2+m2]);
  int kmin = imax(0, imax(l2 - l - m1, l1 + m2 - l));
  int kmax = imin(l1 + l2 - l, imin(l1 - m1, l2 + m2));
  double s = 0.0;
  for (int k = kmin; k <= kmax; ++k) {
    double d = d_FACT[k]*d_FACT[l1+l2-l-k]*d_FACT[l1-m1-k]*d_FACT[l2+m2-k]*
               d_FACT[l-l2+m1+k]*d_FACT[l-l1-m2+k];
    s += ((k & 1) ? -1.0 : 1.0) / d;
  }
  return (float)(pre * s);
}

__device__ __forceinline__ unsigned short f2bf(float x) {
  unsigned int u = __float_as_uint(x);
  unsigned int r = (u + 0x7FFFu + ((u >> 16) & 1u)) >> 16;
  return (unsigned short)r;
}

using bf16x8 = __attribute__((ext_vector_type(8))) short;
using f32x4  = __attribute__((ext_vector_type(4))) float;
using f32x2  = __attribute__((ext_vector_type(2))) float;
using u16x2  = __attribute__((ext_vector_type(2))) unsigned short;
using u16x4  = __attribute__((ext_vector_type(4))) unsigned short;

// -------- k0_pack: W f32 [k][o] -> fragment-major bf16 [ti][nt][ks][lane][8] --------
__global__ __launch_bounds__(256)
void k0_pack(const float* __restrict__ W, unsigned short* __restrict__ ws) {
  __shared__ float sw[256*33];
  const int l = blockIdx.y, ti = blockIdx.x;
  if (ti >= d_NTRI_rt[l]) return;
  const int base = d_CUM_W_rt[l] + ti*8192;
  const int tid = threadIdx.x;
  for (int i = tid; i < 8192; i += 256) {
    const int kl = i >> 5, o = i & 31;
    sw[kl*33 + o] = W[base + i];
  }
  __syncthreads();
  for (int i = tid; i < 8192; i += 256) {
    const int nt = i >> 12, r2 = i & 4095;
    const int ks = r2 >> 9, r3 = r2 & 511;
    const int ln = r3 >> 3, e  = r3 & 7;
    const int o  = nt*16 + (ln & 15);
    const int kl = ks*32 + (ln >> 4)*8 + e;
    ws[base + i] = f2bf(sw[kl*33 + o]);
  }
}

// -------- kcg: precompute CG table (f32) into ws --------
__global__ __launch_bounds__(128)
void kcg(float* __restrict__ CGf) {
  const int gi = blockIdx.x;
  const int l = d_TRI_L_rt[gi], l1 = d_TRI_L1_rt[gi], l2 = d_TRI_L2_rt[gi];
  const int N1 = 2*l1 + 1, NM = 2*l + 1;
  const int idx = threadIdx.x;
  if (idx >= NM * N1) return;
  const int mi = idx / N1, m1i = idx - mi * N1;
  const int m2 = (mi - l) - (m1i - l1);
  float v = (m2 >= -l2 && m2 <= l2) ? cg_coef(l1, m1i-l1, l2, m2, l, mi-l) : 0.f;
  CGf[d_CG_OFF_rt[gi] + idx] = v;
}

// -------- stage-1: wave W computes mi = W, W+4, ... of one z's FF tile --------
// f1/f2 from LDS-staged Fs slice; packed f32 FMA; swizzled u16x2 stores.
template<int L, int L1, int L2, int W>
__device__ __forceinline__ void s1(const float* __restrict__ sFs,
                                   unsigned short* __restrict__ buf,
                                   const float* __restrict__ cg) {
  constexpr int N1 = 2*L1+1, N2 = 2*L2+1, NM = 2*L+1;
  if constexpr (W < NM) {
    const int lane = threadIdx.x & 63, t = lane & 15, h = lane >> 4;
    float f1r[N1], f1i[N1];
    #pragma unroll
    for (int a = 0; a < N1; ++a) {
      const float2 v = *(const float2*)(sFs + (cumf(L1) + a*16 + t) * 2);
      f1r[a] = v.x; f1i[a] = v.y;
    }
    #pragma unroll
    for (int jp = 0; jp < 2; ++jp) {
      f32x2 f2r2[N2], f2i2[N2];
      #pragma unroll
      for (int b = 0; b < N2; ++b) {
        const float4 v = *(const float4*)(sFs + (cumf(L2) + b*16 + h*4 + jp*2) * 2);
        f2r2[b][0] = v.x; f2r2[b][1] = v.z;
        f2i2[b][0] = v.y; f2i2[b][1] = v.w;
      }
      #pragma unroll
      for (int mi = W; mi < NM; mi += 4) {
        f32x2 ar2 = {0.f, 0.f}, ai2 = {0.f, 0.f};
        #pragma unroll
        for (int m1i = 0; m1i < N1; ++m1i) {
          const int m2i = (mi - L) - (m1i - L1) + L2;   // constant after unroll
          if (m2i >= 0 && m2i < N2) {
            const float c   = cg[mi*N1 + m1i];
            const float c1r = c * f1r[m1i];
            const float c1i = c * f1i[m1i];
            const f32x2 c1r2  = {c1r, c1r};
            const f32x2 c1i2  = {c1i, c1i};
            const f32x2 nc1i2 = {-c1i, -c1i};
            ar2 = __builtin_elementwise_fma(c1r2,  f2r2[m2i], ar2);
            ar2 = __builtin_elementwise_fma(nc1i2, f2i2[m2i], ar2);
            ai2 = __builtin_elementwise_fma(c1r2,  f2i2[m2i], ai2);
            ai2 = __builtin_elementwise_fma(c1i2,  f2r2[m2i], ai2);
          }
        }
        u16x2 vr, vi;
        vr[0] = f2bf(ar2[0]); vr[1] = f2bf(ar2[1]);
        vi[0] = f2bf(ai2[0]); vi[1] = f2bf(ai2[1]);
        const int rr  = 2*mi;
        const int kb2 = t*32 + h*8 + jp*4;
        *(u16x2*)((char*)buf + rr*512     + (kb2 ^ (( rr   &7)<<4))) = vr;
        *(u16x2*)((char*)buf + (rr+1)*512 + (kb2 ^ (((rr+1)&7)<<4))) = vi;
      }
    }
  }
}

#define SC(GI,LL,A,B) case GI: if constexpr (LL==L) { \
    if      (w == 0) s1<LL,A,B,0>(sFs, buf, cg); \
    else if (w == 1) s1<LL,A,B,1>(sFs, buf, cg); \
    else if (w == 2) s1<LL,A,B,2>(sFs, buf, cg); \
    else             s1<LL,A,B,3>(sFs, buf, cg); } break;

template<int L>
__device__ __forceinline__ void run_s1(int gi, int w, const float* __restrict__ sFs,
                                       unsigned short* __restrict__ buf,
                                       const float* __restrict__ sCG) {
  constexpr int CGS = L==0?0 : L==1?36 : L==2?216 : L==3?591 : L==4?1151 : 1871;
  const float* cg = sCG + (d_CG_OFF_rt[gi] - CGS);
  switch (gi) {
    SC(0,0,0,0) SC(1,0,1,1) SC(2,0,2,2) SC(3,0,3,3) SC(4,0,4,4) SC(5,0,5,5)
    SC(6,1,0,1) SC(7,1,1,1) SC(8,1,1,2) SC(9,1,2,2) SC(10,1,2,3) SC(11,1,3,3)
    SC(12,1,3,4) SC(13,1,4,4) SC(14,1,4,5) SC(15,1,5,5)
    SC(16,2,0,2) SC(17,2,1,1) SC(18,2,1,2) SC(19,2,1,3) SC(20,2,2,2) SC(21,2,2,3)
    SC(22,2,2,4) SC(23,2,3,3) SC(24,2,3,4) SC(25,2,3,5) SC(26,2,4,4) SC(27,2,4,5)
    SC(28,2,5,5)
    SC(29,3,0,3) SC(30,3,1,2) SC(31,3,1,3) SC(32,3,1,4) SC(33,3,2,2) SC(34,3,2,3)
    SC(35,3,2,4) SC(36,3,2,5) SC(37,3,3,3) SC(38,3,3,4) SC(39,3,3,5) SC(40,3,4,4)
    SC(41,3,4,5) SC(42,3,5,5)
    SC(43,4,0,4) SC(44,4,1,3) SC(45,4,1,4) SC(46,4,1,5) SC(47,4,2,2) SC(48,4,2,3)
    SC(49,4,2,4) SC(50,4,2,5) SC(51,4,3,3) SC(52,4,3,4) SC(53,4,3,5) SC(54,4,4,4)
    SC(55,4,4,5) SC(56,4,5,5)
    SC(57,5,0,5) SC(58,5,1,4) SC(59,5,1,5) SC(60,5,2,3) SC(61,5,2,4) SC(62,5,2,5)
    SC(63,5,3,3) SC(64,5,3,4) SC(65,5,3,5) SC(66,5,4,4) SC(67,5,4,5) SC(68,5,5,5)
    default: break;
  }
}

template<int L>
__device__ __forceinline__ void body(int z, const float* __restrict__ Fs,
                                     const unsigned short* __restrict__ Wp,
                                     const float* __restrict__ CGf,
                                     float* __restrict__ out,
                                     unsigned short (*sFF)[8192],
                                     float* sCG, float* sFs) {
  constexpr int NM = 2*L+1, ROWS = 2*NM, BM = (ROWS+15)&~15, NMT = BM/16;
  constexpr int NTRI = L==0?6 : L==1?10 : L==2?13 : L==5?12 : 14;
  constexpr int TS  = L==0?0 : L==1?6 : L==2?16 : L==3?29 : L==4?43 : 57;
  constexpr int CW  = L==0?0 : L==1?49152 : L==2?131072 : L==3?237568 : L==4?352256 : 466944;
  constexpr int OFF = L==0?0 : L==1?32 : L==2?128 : L==3?288 : L==4?512 : 800;
  constexpr int CGS = L==0?0 : L==1?36 : L==2?216 : L==3?591 : L==4?1151 : 1871;
  constexpr int CGL = L==0?36 : L==1?180 : L==2?375 : L==3?560 : L==4?720 : 792;
  constexpr int KS  = (NMT == 1) ? 4 : 8;

  const int tid = threadIdx.x, lane = tid & 63, w = tid >> 6;

  // ---- block prologue: stage Fs slice + CG into LDS, zero pad rows (both bufs)
  const float* FsZ = Fs + (size_t)z * 1152;
  for (int i = tid; i < 288; i += 256)
    ((float4*)sFs)[i] = ((const float4*)FsZ)[i];
  for (int i = tid; i < CGL; i += 256) sCG[i] = CGf[CGS + i];
  if constexpr (BM > ROWS) {
    constexpr int PADV = (BM - ROWS) * 64;     // u16x4 stores per buffer
    for (int i = tid; i < 2*PADV; i += 256) {
      const int bb = (i >= PADV) ? 1 : 0;
      const int ii = i - bb*PADV;
      const int r = ROWS + (ii >> 6), kq4 = (ii & 63) * 4;
      u16x4 zz = {0,0,0,0};
      *(u16x4*)(&sFF[bb][r*256 + kq4]) = zz;
    }
  }
  __syncthreads();

  // ---- stage-2 per-wave constants
  const int nt    = w & 1;
  const int khalf = (NMT == 1) ? (w >> 1) : 0;
  const int mt    = (NMT == 2) ? (w >> 1) : 0;
  const int row   = mt*16 + (lane & 15);
  const int rowb  = row * 512;
  const int swz   = (row & 7) << 4;
  const int kq    = (lane >> 4) * 16;
  const unsigned short* Bp = Wp + CW + nt*4096 + lane*8;

  f32x4 acc = {0.f,0.f,0.f,0.f};

  // ---- B-register prefetch for triple 0 (independent of stage-1)
  bf16x8 breg[KS];
  {
    const unsigned short* bp = Bp;
    #pragma unroll
    for (int ks0 = 0; ks0 < KS; ++ks0)
      breg[ks0] = *(const bf16x8*)(bp + (khalf*4 + ks0)*512);
  }

  // ---- software-pipelined triple loop: ONE barrier per triple
  run_s1<L>(TS + 0, w, sFs, sFF[0], sCG);
  __syncthreads();

  for (int ti = 0; ti < NTRI; ++ti) {
    if (ti + 1 < NTRI)
      run_s1<L>(TS + ti + 1, w, sFs, sFF[(ti+1)&1], sCG);   // fills other buffer

    const char* bufc = (const char*)sFF[ti&1];
    #pragma unroll
    for (int ks0 = 0; ks0 < KS; ++ks0) {
      const int ks = khalf*4 + ks0;
      const bf16x8 a = *(const bf16x8*)(bufc + rowb + ((ks*64 + kq) ^ swz));
      acc = __builtin_amdgcn_mfma_f32_16x16x32_bf16(a, breg[ks0], acc, 0, 0, 0);
    }
    if (ti + 1 < NTRI) {
      // issue next triple's B loads BEFORE the barrier: they stay in flight
      // across it (register loads need no vmcnt drain at s_barrier) and
      // complete under the barrier + next stage-1.
      const unsigned short* bp = Bp + (ti + 1)*8192;
      #pragma unroll
      for (int ks0 = 0; ks0 < KS; ++ks0)
        breg[ks0] = *(const bf16x8*)(bp + (khalf*4 + ks0)*512);
    }
    __syncthreads();   // next-buffer writes done AND this-buffer reads done
  }

  if constexpr (NMT == 1) {                // cross-wave k-half reduction
    float* red = (float*)sFF[0];
    if (w >= 2) {
      #pragma unroll
      for (int j = 0; j < 4; ++j) red[(nt*64 + lane)*4 + j] = acc[j];
    }
    __syncthreads();
    if (w >= 2) return;
    #pragma unroll
    for (int j = 0; j < 4; ++j) acc[j] += red[(nt*64 + lane)*4 + j];
  }

  const int col = nt*16 + (lane & 15);
  #pragma unroll
  for (int j = 0; j < 4; ++j) {
    const int r2 = mt*16 + (lane >> 4)*4 + j;
    if (r2 < ROWS) {
      out[((size_t)z*1152 + OFF + (r2 >> 1)*32 + col)*2 + (r2 & 1)] = acc[j];
    }
  }
}

__global__ __launch_bounds__(256, 2)
void fused_all(const float* __restrict__ Fs, const unsigned short* __restrict__ Wp,
               const float* __restrict__ CGf, float* __restrict__ out) {
  __shared__ unsigned short sFF[2][8192];   // 32 KB double-buffered FF tile
  __shared__ float sCG[792];                // 3.2 KB CG slice
  __shared__ float sFs[1152];               // 4.6 KB Fs slice for this z
  const int g = blockIdx.x >> 8;            // 0..5, heavy l first
  const int z = blockIdx.x & 255;
  switch (g) {
    case 0: body<5>(z, Fs, Wp, CGf, out, sFF, sCG, sFs); break;
    case 1: body<4>(z, Fs, Wp, CGf, out, sFF, sCG, sFs); break;
    case 2: body<3>(z, Fs, Wp, CGf, out, sFF, sCG, sFs); break;
    case 3: body<2>(z, Fs, Wp, CGf, out, sFF, sCG, sFs); break;
    case 4: body<1>(z, Fs, Wp, CGf, out, sFF, sCG, sFs); break;
    case 5: body<0>(z, Fs, Wp, CGf, out, sFF, sCG, sFs); break;
  }
}

// ---------------- fallback: round-1 fused VALU kernel ----------------
__global__ __launch_bounds__(256)
void cgbn_fused(const float* __restrict__ Fs, const float* __restrict__ W,
                float* __restrict__ out) {
  const int l   = blockIdx.x;
  const int z   = blockIdx.y;
  const int tid = threadIdx.x;

  __shared__ float sF1[11*32];
  __shared__ float sF2[11*32];
  __shared__ float sFFb[24*256];
  __shared__ float sCGb[14*121];

  const int ntri = d_NTRI_rt[l];
  const int tst  = d_TRI_START_rt[l];

  for (int idx = tid; idx < ntri * 121; idx += 256) {
    int ti  = idx / 121;
    int rem = idx - ti * 121;
    int mi  = rem / 11;
    int m1i = rem - mi * 11;
    int l1 = d_TRI_L1_rt[tst + ti], l2 = d_TRI_L2_rt[tst + ti];
    float v = 0.f;
    if (mi <= 2*l && m1i <= 2*l1) {
      int m = mi - l, m1 = m1i - l1, m2 = m - m1;
      if (m2 >= -l2 && m2 <= l2) v = cg_coef(l1, m1, l2, m2, l, m);
    }
    sCGb[idx] = v;
  }

  const int tt = tid >> 4;
  const int ss = tid & 15;
  const int r0 = tid >> 5;
  const int oo = tid & 31;

  float acc0 = 0.f, acc1 = 0.f, acc2 = 0.f;

  const int twoLp1 = 2*l + 1;
  const int R = twoLp1 * 2;
  const float* FsZ = Fs + (size_t)z * (576*2);
  const int cumF[NL] = {0,16,64,144,256,400};

  for (int ti = 0; ti < ntri; ++ti) {
    const int l1 = d_TRI_L1_rt[tst + ti], l2 = d_TRI_L2_rt[tst + ti];
    const int n1 = (2*l1 + 1) * 32, n2 = (2*l2 + 1) * 32;

    __syncthreads();
    for (int i = tid; i < n1; i += 256) sF1[i] = FsZ[cumF[l1]*2 + i];
    for (int i = tid; i < n2; i += 256) sF2[i] = FsZ[cumF[l2]*2 + i];
    __syncthreads();

    for (int mi = 0; mi < twoLp1; ++mi) {
      const int m  = mi - l;
      const int lo = imax(-l1, m - l2), hi = imin(l1, m + l2);
      float ar = 0.f, ai = 0.f;
      for (int m1 = lo; m1 <= hi; ++m1) {
        const float cg  = sCGb[ti*121 + mi*11 + (m1 + l1)];
        const int   a   = (m1 + l1) * 32 + tt * 2;
        const int   b   = ((m - m1) + l2) * 32 + ss * 2;
        const float f1r = sF1[a],     f1i = sF1[a + 1];
        const float f2r = sF2[b],     f2i = sF2[b + 1];
        ar = fmaf(cg, f1r*f2r - f1i*f2i, ar);
        ai = fmaf(cg, f1r*f2i + f1i*f2r, ai);
      }
      sFFb[(2*mi    ) * 256 + tid] = ar;
      sFFb[(2*mi + 1) * 256 + tid] = ai;
    }
    __syncthreads();

    const float* wp  = W + d_CUM_W_rt[l] + ti * 8192 + oo;
    const float* fr0 = sFFb + (r0     ) * 256;
    const float* fr1 = sFFb + (r0 + 8 ) * 256;
    const float* fr2 = sFFb + (r0 + 16) * 256;
    #pragma unroll 4
    for (int k = 0; k < 256; ++k) {
      const float wv = wp[k * 32];
      acc0 = fmaf(fr0[k], wv, acc0);
      acc1 = fmaf(fr1[k], wv, acc1);
      acc2 = fmaf(fr2[k], wv, acc2);
    }
  }

  const float accs[3] = {acc0, acc1, acc2};
  #pragma unroll
  for (int j = 0; j < 3; ++j) {
    const int row = r0 + 8*j;
    if (row < R) {
      const int m = row >> 1, c = row & 1;
      out[((size_t)z * 1152 + d_OUT_OFF_rt[l] + m * 32 + oo) * 2 + c] = accs[j];
    }
  }
}

extern "C" void kernel_launch(void* const* d_in, const int* in_sizes, int n_in,
                              void* d_out, int out_size, void* d_ws, size_t ws_size,
                              hipStream_t stream) {
  const float* Fs = (const float*)d_in[0];
  const float* W  = (const float*)d_in[1];
  float* out = (float*)d_out;

  // ws layout: [0, 1130496) bytes: packed Wfrag bf16; [1130496, +10652): CG f32
  if (ws_size >= 1141148ULL) {
    unsigned short* ws = (unsigned short*)d_ws;
    float* CGf = (float*)((char*)d_ws + 1130496);
    hipLaunchKernelGGL(k0_pack, dim3(14, 6), dim3(256), 0, stream, W, ws);
    hipLaunchKernelGGL(kcg, dim3(69), dim3(128), 0, stream, CGf);
    hipLaunchKernelGGL(fused_all, dim3(1536), dim3(256), 0, stream, Fs, ws, CGf, out);
  } else {
    hipLaunchKernelGGL(cgbn_fused, dim3(6, 256), dim3(256), 0, stream, Fs, W, out);
  }
}

// Round 20
// 52.097 us; speedup vs baseline: 1.1371x; 1.1371x over previous
//
#include <hip/hip_runtime.h>

// CG tensor product, fully fused MFMA design (FINAL = round 15/18, 52.1 us):
//  k0_pack:  W f32 [l][k][o] -> fragment-major bf16 Wfrag (LDS transpose)
//  kcg:      Racah CG coefficients -> f32 table in ws (fp64 isolated here)
//  fused_all: 1536 blocks = 6 l-groups x 256 z. Fs slice + CG staged in LDS;
//             per triple: stage-1 packed-f32 CG contraction -> swizzled LDS FF
//             tile (double-buffered, ONE barrier/triple); stage-2 mfma
//             16x16x32 bf16; accumulate across triples; direct store.
// Fallback: round-1 fused VALU kernel if ws too small.

#define NL 6

__constant__ int d_CUM_W_rt[NL]  = {0,49152,131072,237568,352256,466944};
__constant__ int d_OUT_OFF_rt[NL]= {0,32,128,288,512,800};
__constant__ int d_NTRI_rt[NL]   = {6,10,13,14,14,12};
__constant__ int d_TRI_START_rt[NL] = {0,6,16,29,43,57};
__constant__ int d_TRI_L_rt[69] = {
  0,0,0,0,0,0,
  1,1,1,1,1,1,1,1,1,1,
  2,2,2,2,2,2,2,2,2,2,2,2,2,
  3,3,3,3,3,3,3,3,3,3,3,3,3,3,
  4,4,4,4,4,4,4,4,4,4,4,4,4,4,
  5,5,5,5,5,5,5,5,5,5,5,5};
__constant__ int d_TRI_L1_rt[69] = {
  0,1,2,3,4,5,
  0,1,1,2,2,3,3,4,4,5,
  0,1,1,1,2,2,2,3,3,3,4,4,5,
  0,1,1,1,2,2,2,2,3,3,3,4,4,5,
  0,1,1,1,2,2,2,2,3,3,3,4,4,5,
  0,1,1,2,2,2,3,3,3,4,4,5};
__constant__ int d_TRI_L2_rt[69] = {
  0,1,2,3,4,5,
  1,1,2,2,3,3,4,4,5,5,
  2,1,2,3,2,3,4,3,4,5,4,5,5,
  3,2,3,4,2,3,4,5,3,4,5,4,5,5,
  4,3,4,5,2,3,4,5,3,4,5,4,5,5,
  5,4,5,3,4,5,3,4,5,4,5,5};
// cumulative offsets of NM*N1 CG entries per global triple
__constant__ int d_CG_OFF_rt[69] = {
  0,1,4,9,16,25,
  36,39,48,57,72,87,108,129,156,183,
  216,221,236,251,266,291,316,341,376,411,446,491,536,
  591,598,619,640,661,696,731,766,801,850,899,948,1011,1074,
  1151,1160,1187,1214,1241,1286,1331,1376,1421,1484,1547,1610,1691,1772,
  1871,1882,1915,1948,2003,2058,2113,2190,2267,2344,2443,2542};
// total CG entries: 2663

__constant__ double d_FACT[17] = {
  1.0,1.0,2.0,6.0,24.0,120.0,720.0,5040.0,40320.0,362880.0,
  3628800.0,39916800.0,479001600.0,6227020800.0,87178291200.0,
  1307674368000.0,20922789888000.0};

__device__ __forceinline__ int imax(int a, int b){ return a > b ? a : b; }
__device__ __forceinline__ int imin(int a, int b){ return a < b ? a : b; }
__device__ __forceinline__ constexpr int cumf(int l) {
  return l==0?0 : l==1?16 : l==2?64 : l==3?144 : l==4?256 : 400;
}

__device__ float cg_coef(int l1, int m1, int l2, int m2, int l, int m) {
  double pre = sqrt((double)(2*l+1) * d_FACT[l+l1-l2] * d_FACT[l-l1+l2] *
                    d_FACT[l1+l2-l] / d_FACT[l1+l2+l+1]);
  pre *= sqrt(d_FACT[l+m]*d_FACT[l-m]*d_FACT[l1-m1]*d_FACT[l1+m1]*
              d_FACT[l2-m2]*d_FACT[l2+m2]);
  int kmin = imax(0, imax(l2 - l - m1, l1 + m2 - l));
  int kmax = imin(l1 + l2 - l, imin(l1 - m1, l2 + m2));
  double s = 0.0;
  for (int k = kmin; k <= kmax; ++k) {
    double d = d_FACT[k]*d_FACT[l1+l2-l-k]*d_FACT[l1-m1-k]*d_FACT[l2+m2-k]*
               d_FACT[l-l2+m1+k]*d_FACT[l-l1-m2+k];
    s += ((k & 1) ? -1.0 : 1.0) / d;
  }
  return (float)(pre * s);
}

__device__ __forceinline__ unsigned short f2bf(float x) {
  unsigned int u = __float_as_uint(x);
  unsigned int r = (u + 0x7FFFu + ((u >> 16) & 1u)) >> 16;
  return (unsigned short)r;
}

using bf16x8 = __attribute__((ext_vector_type(8))) short;
using f32x4  = __attribute__((ext_vector_type(4))) float;
using f32x2  = __attribute__((ext_vector_type(2))) float;
using u16x2  = __attribute__((ext_vector_type(2))) unsigned short;
using u16x4  = __attribute__((ext_vector_type(4))) unsigned short;

// -------- k0_pack: W f32 [k][o] -> fragment-major bf16 [ti][nt][ks][lane][8] --------
__global__ __launch_bounds__(256)
void k0_pack(const float* __restrict__ W, unsigned short* __restrict__ ws) {
  __shared__ float sw[256*33];
  const int l = blockIdx.y, ti = blockIdx.x;
  if (ti >= d_NTRI_rt[l]) return;
  const int base = d_CUM_W_rt[l] + ti*8192;
  const int tid = threadIdx.x;
  for (int i = tid; i < 8192; i += 256) {
    const int kl = i >> 5, o = i & 31;
    sw[kl*33 + o] = W[base + i];
  }
  __syncthreads();
  for (int i = tid; i < 8192; i += 256) {
    const int nt = i >> 12, r2 = i & 4095;
    const int ks = r2 >> 9, r3 = r2 & 511;
    const int ln = r3 >> 3, e  = r3 & 7;
    const int o  = nt*16 + (ln & 15);
    const int kl = ks*32 + (ln >> 4)*8 + e;
    ws[base + i] = f2bf(sw[kl*33 + o]);
  }
}

// -------- kcg: precompute CG table (f32) into ws --------
__global__ __launch_bounds__(128)
void kcg(float* __restrict__ CGf) {
  const int gi = blockIdx.x;
  const int l = d_TRI_L_rt[gi], l1 = d_TRI_L1_rt[gi], l2 = d_TRI_L2_rt[gi];
  const int N1 = 2*l1 + 1, NM = 2*l + 1;
  const int idx = threadIdx.x;
  if (idx >= NM * N1) return;
  const int mi = idx / N1, m1i = idx - mi * N1;
  const int m2 = (mi - l) - (m1i - l1);
  float v = (m2 >= -l2 && m2 <= l2) ? cg_coef(l1, m1i-l1, l2, m2, l, mi-l) : 0.f;
  CGf[d_CG_OFF_rt[gi] + idx] = v;
}

// -------- stage-1: wave W computes mi = W, W+4, ... of one z's FF tile --------
// f1/f2 from LDS-staged Fs slice; j-pair processed with PACKED f32 FMA
// (v_pk_fma_f32); j split in 2 passes; swizzled u16x2 stores.
template<int L, int L1, int L2, int W>
__device__ __forceinline__ void s1(const float* __restrict__ sFs,
                                   unsigned short* __restrict__ buf,
                                   const float* __restrict__ cg) {
  constexpr int N1 = 2*L1+1, N2 = 2*L2+1, NM = 2*L+1;
  if constexpr (W < NM) {
    const int lane = threadIdx.x & 63, t = lane & 15, h = lane >> 4;
    float f1r[N1], f1i[N1];
    #pragma unroll
    for (int a = 0; a < N1; ++a) {
      const float2 v = *(const float2*)(sFs + (cumf(L1) + a*16 + t) * 2);
      f1r[a] = v.x; f1i[a] = v.y;
    }
    #pragma unroll
    for (int jp = 0; jp < 2; ++jp) {
      f32x2 f2r2[N2], f2i2[N2];
      #pragma unroll
      for (int b = 0; b < N2; ++b) {
        const float4 v = *(const float4*)(sFs + (cumf(L2) + b*16 + h*4 + jp*2) * 2);
        f2r2[b][0] = v.x; f2r2[b][1] = v.z;
        f2i2[b][0] = v.y; f2i2[b][1] = v.w;
      }
      #pragma unroll
      for (int mi = W; mi < NM; mi += 4) {
        f32x2 ar2 = {0.f, 0.f}, ai2 = {0.f, 0.f};
        #pragma unroll
        for (int m1i = 0; m1i < N1; ++m1i) {
          const int m2i = (mi - L) - (m1i - L1) + L2;   // constant after unroll
          if (m2i >= 0 && m2i < N2) {
            const float c   = cg[mi*N1 + m1i];
            const float c1r = c * f1r[m1i];
            const float c1i = c * f1i[m1i];
            const f32x2 c1r2  = {c1r, c1r};
            const f32x2 c1i2  = {c1i, c1i};
            const f32x2 nc1i2 = {-c1i, -c1i};
            ar2 = __builtin_elementwise_fma(c1r2,  f2r2[m2i], ar2);
            ar2 = __builtin_elementwise_fma(nc1i2, f2i2[m2i], ar2);
            ai2 = __builtin_elementwise_fma(c1r2,  f2i2[m2i], ai2);
            ai2 = __builtin_elementwise_fma(c1i2,  f2r2[m2i], ai2);
          }
        }
        u16x2 vr, vi;
        vr[0] = f2bf(ar2[0]); vr[1] = f2bf(ar2[1]);
        vi[0] = f2bf(ai2[0]); vi[1] = f2bf(ai2[1]);
        const int rr  = 2*mi;
        const int kb2 = t*32 + h*8 + jp*4;
        *(u16x2*)((char*)buf + rr*512     + (kb2 ^ (( rr   &7)<<4))) = vr;
        *(u16x2*)((char*)buf + (rr+1)*512 + (kb2 ^ (((rr+1)&7)<<4))) = vi;
      }
    }
  }
}

#define SC(GI,LL,A,B) case GI: if constexpr (LL==L) { \
    if      (w == 0) s1<LL,A,B,0>(sFs, buf, cg); \
    else if (w == 1) s1<LL,A,B,1>(sFs, buf, cg); \
    else if (w == 2) s1<LL,A,B,2>(sFs, buf, cg); \
    else             s1<LL,A,B,3>(sFs, buf, cg); } break;

template<int L>
__device__ __forceinline__ void run_s1(int gi, int w, const float* __restrict__ sFs,
                                       unsigned short* __restrict__ buf,
                                       const float* __restrict__ sCG) {
  constexpr int CGS = L==0?0 : L==1?36 : L==2?216 : L==3?591 : L==4?1151 : 1871;
  const float* cg = sCG + (d_CG_OFF_rt[gi] - CGS);
  switch (gi) {
    SC(0,0,0,0) SC(1,0,1,1) SC(2,0,2,2) SC(3,0,3,3) SC(4,0,4,4) SC(5,0,5,5)
    SC(6,1,0,1) SC(7,1,1,1) SC(8,1,1,2) SC(9,1,2,2) SC(10,1,2,3) SC(11,1,3,3)
    SC(12,1,3,4) SC(13,1,4,4) SC(14,1,4,5) SC(15,1,5,5)
    SC(16,2,0,2) SC(17,2,1,1) SC(18,2,1,2) SC(19,2,1,3) SC(20,2,2,2) SC(21,2,2,3)
    SC(22,2,2,4) SC(23,2,3,3) SC(24,2,3,4) SC(25,2,3,5) SC(26,2,4,4) SC(27,2,4,5)
    SC(28,2,5,5)
    SC(29,3,0,3) SC(30,3,1,2) SC(31,3,1,3) SC(32,3,1,4) SC(33,3,2,2) SC(34,3,2,3)
    SC(35,3,2,4) SC(36,3,2,5) SC(37,3,3,3) SC(38,3,3,4) SC(39,3,3,5) SC(40,3,4,4)
    SC(41,3,4,5) SC(42,3,5,5)
    SC(43,4,0,4) SC(44,4,1,3) SC(45,4,1,4) SC(46,4,1,5) SC(47,4,2,2) SC(48,4,2,3)
    SC(49,4,2,4) SC(50,4,2,5) SC(51,4,3,3) SC(52,4,3,4) SC(53,4,3,5) SC(54,4,4,4)
    SC(55,4,4,5) SC(56,4,5,5)
    SC(57,5,0,5) SC(58,5,1,4) SC(59,5,1,5) SC(60,5,2,3) SC(61,5,2,4) SC(62,5,2,5)
    SC(63,5,3,3) SC(64,5,3,4) SC(65,5,3,5) SC(66,5,4,4) SC(67,5,4,5) SC(68,5,5,5)
    default: break;
  }
}

template<int L>
__device__ __forceinline__ void body(int z, const float* __restrict__ Fs,
                                     const unsigned short* __restrict__ Wp,
                                     const float* __restrict__ CGf,
                                     float* __restrict__ out,
                                     unsigned short (*sFF)[8192],
                                     float* sCG, float* sFs) {
  constexpr int NM = 2*L+1, ROWS = 2*NM, BM = (ROWS+15)&~15, NMT = BM/16;
  constexpr int NTRI = L==0?6 : L==1?10 : L==2?13 : L==5?12 : 14;
  constexpr int TS  = L==0?0 : L==1?6 : L==2?16 : L==3?29 : L==4?43 : 57;
  constexpr int CW  = L==0?0 : L==1?49152 : L==2?131072 : L==3?237568 : L==4?352256 : 466944;
  constexpr int OFF = L==0?0 : L==1?32 : L==2?128 : L==3?288 : L==4?512 : 800;
  constexpr int CGS = L==0?0 : L==1?36 : L==2?216 : L==3?591 : L==4?1151 : 1871;
  constexpr int CGL = L==0?36 : L==1?180 : L==2?375 : L==3?560 : L==4?720 : 792;

  const int tid = threadIdx.x, lane = tid & 63, w = tid >> 6;

  // ---- block prologue: stage Fs slice + CG into LDS, zero pad rows (both bufs)
  const float* FsZ = Fs + (size_t)z * 1152;
  for (int i = tid; i < 288; i += 256)
    ((float4*)sFs)[i] = ((const float4*)FsZ)[i];
  for (int i = tid; i < CGL; i += 256) sCG[i] = CGf[CGS + i];
  if constexpr (BM > ROWS) {
    constexpr int PADV = (BM - ROWS) * 64;     // u16x4 stores per buffer
    for (int i = tid; i < 2*PADV; i += 256) {
      const int bb = (i >= PADV) ? 1 : 0;
      const int ii = i - bb*PADV;
      const int r = ROWS + (ii >> 6), kq4 = (ii & 63) * 4;
      u16x4 zz = {0,0,0,0};
      *(u16x4*)(&sFF[bb][r*256 + kq4]) = zz;
    }
  }
  __syncthreads();

  // ---- stage-2 per-wave constants
  const int nt    = w & 1;
  const int khalf = (NMT == 1) ? (w >> 1) : 0;
  const int mt    = (NMT == 2) ? (w >> 1) : 0;
  const int row   = mt*16 + (lane & 15);
  const int rowb  = row * 512;
  const int swz   = (row & 7) << 4;
  const int kq    = (lane >> 4) * 16;
  const unsigned short* Bp = Wp + CW + nt*4096 + lane*8;

  f32x4 acc = {0.f,0.f,0.f,0.f};

  // ---- software-pipelined triple loop: ONE barrier per triple
  run_s1<L>(TS + 0, w, sFs, sFF[0], sCG);
  __syncthreads();

  for (int ti = 0; ti < NTRI; ++ti) {
    if (ti + 1 < NTRI)
      run_s1<L>(TS + ti + 1, w, sFs, sFF[(ti+1)&1], sCG);   // fills other buffer

    const unsigned short* bp = Bp + ti*8192;
    const char* bufc = (const char*)sFF[ti&1];
    #pragma unroll
    for (int ks0 = 0; ks0 < (NMT == 1 ? 4 : 8); ++ks0) {
      const int ks = khalf*4 + ks0;
      const bf16x8 b = *(const bf16x8*)(bp + ks*512);
      const bf16x8 a = *(const bf16x8*)(bufc + rowb + ((ks*64 + kq) ^ swz));
      acc = __builtin_amdgcn_mfma_f32_16x16x32_bf16(a, b, acc, 0, 0, 0);
    }
    __syncthreads();   // next-buffer writes done AND this-buffer reads done
  }

  if constexpr (NMT == 1) {                // cross-wave k-half reduction
    float* red = (float*)sFF[0];
    if (w >= 2) {
      #pragma unroll
      for (int j = 0; j < 4; ++j) red[(nt*64 + lane)*4 + j] = acc[j];
    }
    __syncthreads();
    if (w >= 2) return;
    #pragma unroll
    for (int j = 0; j < 4; ++j) acc[j] += red[(nt*64 + lane)*4 + j];
  }

  const int col = nt*16 + (lane & 15);
  #pragma unroll
  for (int j = 0; j < 4; ++j) {
    const int r2 = mt*16 + (lane >> 4)*4 + j;
    if (r2 < ROWS) {
      out[((size_t)z*1152 + OFF + (r2 >> 1)*32 + col)*2 + (r2 & 1)] = acc[j];
    }
  }
}

__global__ __launch_bounds__(256, 2)
void fused_all(const float* __restrict__ Fs, const unsigned short* __restrict__ Wp,
               const float* __restrict__ CGf, float* __restrict__ out) {
  __shared__ unsigned short sFF[2][8192];   // 32 KB double-buffered FF tile
  __shared__ float sCG[792];                // 3.2 KB CG slice
  __shared__ float sFs[1152];               // 4.6 KB Fs slice for this z
  const int g = blockIdx.x >> 8;            // 0..5, heavy l first
  const int z = blockIdx.x & 255;
  switch (g) {
    case 0: body<5>(z, Fs, Wp, CGf, out, sFF, sCG, sFs); break;
    case 1: body<4>(z, Fs, Wp, CGf, out, sFF, sCG, sFs); break;
    case 2: body<3>(z, Fs, Wp, CGf, out, sFF, sCG, sFs); break;
    case 3: body<2>(z, Fs, Wp, CGf, out, sFF, sCG, sFs); break;
    case 4: body<1>(z, Fs, Wp, CGf, out, sFF, sCG, sFs); break;
    case 5: body<0>(z, Fs, Wp, CGf, out, sFF, sCG, sFs); break;
  }
}

// ---------------- fallback: round-1 fused VALU kernel ----------------
__global__ __launch_bounds__(256)
void cgbn_fused(const float* __restrict__ Fs, const float* __restrict__ W,
                float* __restrict__ out) {
  const int l   = blockIdx.x;
  const int z   = blockIdx.y;
  const int tid = threadIdx.x;

  __shared__ float sF1[11*32];
  __shared__ float sF2[11*32];
  __shared__ float sFFb[24*256];
  __shared__ float sCGb[14*121];

  const int ntri = d_NTRI_rt[l];
  const int tst  = d_TRI_START_rt[l];

  for (int idx = tid; idx < ntri * 121; idx += 256) {
    int ti  = idx / 121;
    int rem = idx - ti * 121;
    int mi  = rem / 11;
    int m1i = rem - mi * 11;
    int l1 = d_TRI_L1_rt[tst + ti], l2 = d_TRI_L2_rt[tst + ti];
    float v = 0.f;
    if (mi <= 2*l && m1i <= 2*l1) {
      int m = mi - l, m1 = m1i - l1, m2 = m - m1;
      if (m2 >= -l2 && m2 <= l2) v = cg_coef(l1, m1, l2, m2, l, m);
    }
    sCGb[idx] = v;
  }

  const int tt = tid >> 4;
  const int ss = tid & 15;
  const int r0 = tid >> 5;
  const int oo = tid & 31;

  float acc0 = 0.f, acc1 = 0.f, acc2 = 0.f;

  const int twoLp1 = 2*l + 1;
  const int R = twoLp1 * 2;
  const float* FsZ = Fs + (size_t)z * (576*2);
  const int cumF[NL] = {0,16,64,144,256,400};

  for (int ti = 0; ti < ntri; ++ti) {
    const int l1 = d_TRI_L1_rt[tst + ti], l2 = d_TRI_L2_rt[tst + ti];
    const int n1 = (2*l1 + 1) * 32, n2 = (2*l2 + 1) * 32;

    __syncthreads();
    for (int i = tid; i < n1; i += 256) sF1[i] = FsZ[cumF[l1]*2 + i];
    for (int i = tid; i < n2; i += 256) sF2[i] = FsZ[cumF[l2]*2 + i];
    __syncthreads();

    for (int mi = 0; mi < twoLp1; ++mi) {
      const int m  = mi - l;
      const int lo = imax(-l1, m - l2), hi = imin(l1, m + l2);
      float ar = 0.f, ai = 0.f;
      for (int m1 = lo; m1 <= hi; ++m1) {
        const float cg  = sCGb[ti*121 + mi*11 + (m1 + l1)];
        const int   a   = (m1 + l1) * 32 + tt * 2;
        const int   b   = ((m - m1) + l2) * 32 + ss * 2;
        const float f1r = sF1[a],     f1i = sF1[a + 1];
        const float f2r = sF2[b],     f2i = sF2[b + 1];
        ar = fmaf(cg, f1r*f2r - f1i*f2i, ar);
        ai = fmaf(cg, f1r*f2i + f1i*f2r, ai);
      }
      sFFb[(2*mi    ) * 256 + tid] = ar;
      sFFb[(2*mi + 1) * 256 + tid] = ai;
    }
    __syncthreads();

    const float* wp  = W + d_CUM_W_rt[l] + ti * 8192 + oo;
    const float* fr0 = sFFb + (r0     ) * 256;
    const float* fr1 = sFFb + (r0 + 8 ) * 256;
    const float* fr2 = sFFb + (r0 + 16) * 256;
    #pragma unroll 4
    for (int k = 0; k < 256; ++k) {
      const float wv = wp[k * 32];
      acc0 = fmaf(fr0[k], wv, acc0);
      acc1 = fmaf(fr1[k], wv, acc1);
      acc2 = fmaf(fr2[k], wv, acc2);
    }
  }

  const float accs[3] = {acc0, acc1, acc2};
  #pragma unroll
  for (int j = 0; j < 3; ++j) {
    const int row = r0 + 8*j;
    if (row < R) {
      const int m = row >> 1, c = row & 1;
      out[((size_t)z * 1152 + d_OUT_OFF_rt[l] + m * 32 + oo) * 2 + c] = accs[j];
    }
  }
}

extern "C" void kernel_launch(void* const* d_in, const int* in_sizes, int n_in,
                              void* d_out, int out_size, void* d_ws, size_t ws_size,
                              hipStream_t stream) {
  const float* Fs = (const float*)d_in[0];
  const float* W  = (const float*)d_in[1];
  float* out = (float*)d_out;

  // ws layout: [0, 1130496) bytes: packed Wfrag bf16; [1130496, +10652): CG f32
  if (ws_size >= 1141148ULL) {
    unsigned short* ws = (unsigned short*)d_ws;
    float* CGf = (float*)((char*)d_ws + 1130496);
    hipLaunchKernelGGL(k0_pack, dim3(14, 6), dim3(256), 0, stream, W, ws);
    hipLaunchKernelGGL(kcg, dim3(69), dim3(128), 0, stream, CGf);
    hipLaunchKernelGGL(fused_all, dim3(1536), dim3(256), 0, stream, Fs, ws, CGf, out);
  } else {
    hipLaunchKernelGGL(cgbn_fused, dim3(6, 256), dim3(256), 0, stream, Fs, W, out);
  }
}